// Round 3
// baseline (92.062 us; speedup 1.0000x reference)
//
#include <hip/hip_runtime.h>
#include <math.h>

#define EPSF     1e-12f
#define INV_4PI  0.07957747154594767f
#define LOG2E    1.4426950408889634f

typedef float v2f __attribute__((ext_vector_type(2)));

#if __has_builtin(__builtin_elementwise_fma)
#define FMA2(a, b, c) __builtin_elementwise_fma((a), (b), (c))
#else
#define FMA2(a, b, c) ((a) * (b) + (c))
#endif

// hardware exp2: single v_exp_f32 per element (R1 showed poly replacement
// doubles issue volume; 1 instr/exp is the floor).
#define EXP2(x) __builtin_amdgcn_exp2f(x)

__device__ __forceinline__ v2f bcast(float x) { v2f r; r.x = x; r.y = x; return r; }

// Z = z_approxbis(f), f already clipped to [0, 0.999999]
__device__ __forceinline__ float zapprox(float f) {
    float f2 = f * f;
    float f4 = f2 * f2;
    float f6 = f4 * f2;
    float f8 = f4 * f4;
    float denom = 3.0f - 1.00651f * f2 - 0.962251f * f4 + 1.47353f * f6 - 0.48953f * f8;
    denom = fmaxf(denom, EPSF);
    float p = 1.0f - 2.0f * (1.0f - f) * (1.0f + 1.01524f * f) / denom;
    return 2.0f * f / fmaxf(1.0f - p, 1e-6f);
}

// z / sinh(z), z >= 0
__device__ __forceinline__ float z_over_sinh(float z) {
    float zz = z * z;
    float series = 1.0f - zz / 6.0f + zz * zz / 120.0f;
    float E = __expf(z);
    float s = 0.5f * (E - 1.0f / E);
    float r = z / s;           // NaN at z==0, discarded by select
    return (z < 1e-4f) ? series : r;
}

// per-species: g(dir) = 2^(zx*dx + zy*dy + zz*dz + la)
__device__ __forceinline__ float4 setup_spec(float N, float Fx, float Fy, float Fz) {
    N = fmaxf(N, EPSF);
    float nf = sqrtf(Fx * Fx + Fy * Fy + Fz * Fz);
    float f  = fminf(fmaxf(nf / N, 0.0f), 0.999999f);
    float Z  = zapprox(f);
    float A  = N * INV_4PI * z_over_sinh(Z);
    float sc = Z * LOG2E / fmaxf(nf, EPSF);
    return make_float4(Fx * sc, Fy * sc, Fz * sc, log2f(A));
}

// ---- kernel 1: per-(batch,species) Spec precompute -> d_ws --------------
__global__ __launch_bounds__(256) void spec_kernel(
    const float* __restrict__ F4, float4* __restrict__ ws, int B)
{
    int t = blockIdx.x * blockDim.x + threadIdx.x;
    if (t >= 4 * B) return;
    int b = t >> 2, s = t & 3;
    const float4* row = (const float4*)(F4 + (size_t)b * 24);
    float N, Fx, Fy, Fz;
    if (s == 0) {                       // e
        float4 a = row[0];  N = a.w; Fx = a.x; Fy = a.y; Fz = a.z;
    } else if (s == 1) {                // ebar
        float4 a = row[3];  N = a.w; Fx = a.x; Fy = a.y; Fz = a.z;
    } else if (s == 2) {                // x = mean(flavors 1,2) of nu
        float4 a = row[1], c = row[2];
        N = 0.5f * (a.w + c.w); Fx = 0.5f * (a.x + c.x);
        Fy = 0.5f * (a.y + c.y); Fz = 0.5f * (a.z + c.z);
    } else {                            // xbar
        float4 a = row[4], c = row[5];
        N = 0.5f * (a.w + c.w); Fx = 0.5f * (a.x + c.x);
        Fy = 0.5f * (a.y + c.y); Fz = 0.5f * (a.z + c.z);
    }
    ws[(size_t)b * 4 + s] = setup_spec(N, Fx, Fy, Fz);
}

__device__ __forceinline__ void add4(float4& a, const float4 b) {
    a.x += b.x; a.y += b.y; a.z += b.z; a.w += b.w;
}

// ---- kernel 2: hot quadrature loop --------------------------------------
// R2 post-mortem: issue volume near-minimal but busy% stuck ~60% (in-loop
// ds_read latency + lockstep waves + shfl-chain epilogue + mask tail).
// Restructure for wave-uniform quadrature:
//   lane  = batch (64 batches/wave), species packed in v2f as (e,ebar)|(x,xbar)
//   wave  = one of 16 chunks of the 400 stored dirs (25 each, exact)
//   block = 1024 thr = 16 waves over the SAME 64 batches; cross-wave LDS
//           tree-reduce once per block (no per-iter shuffles)
// Quadrature comes from SGPR scalar loads (uniform index via readfirstlane),
// prefetched one iteration ahead -> loop body is pure VALU, no lgkm stalls.
// Antipodal trick kept: t(-q) = 2*la - t(+q); antipode moments via fma(.,-q).
// Species packing makes uv=(u,v)=qw*(g01-g23) one pk_sub+pk_mul; the
// delta>=0 mask is one v_cmp + 2 cndmask (same cond for both halves).
// P/N sides processed sequentially (not s/d) to keep live set small;
// __launch_bounds__(1024,8) pins VGPR<=64 -> 2 blocks/CU = 8 waves/SIMD.
__global__ __launch_bounds__(1024, 8) void box3d_kernel(
    const float4* __restrict__ ws,
    const float* __restrict__ dxp, const float* __restrict__ dyp,
    const float* __restrict__ dzp, const float* __restrict__ qwp,
    float* __restrict__ out, int B, int ndir)
{
    __shared__ float4 red[16][64][3];          // 49152 B

    const int lane = threadIdx.x & 63;
    const int w    = __builtin_amdgcn_readfirstlane(threadIdx.x >> 6);   // 0..15
    const int b    = blockIdx.x * 64 + lane;
    const bool live = (b < B);

    // per-lane species constants, packed (e,ebar) and (x,xbar)
    v2f zx01, zy01, zz01, la01, zx23, zy23, zz23, la23;
    if (live) {
        const float4* wsb = ws + (size_t)b * 4;
        float4 s0 = wsb[0], s1 = wsb[1], s2 = wsb[2], s3 = wsb[3];
        zx01.x = s0.x; zx01.y = s1.x;  zx23.x = s2.x; zx23.y = s3.x;
        zy01.x = s0.y; zy01.y = s1.y;  zy23.x = s2.y; zy23.y = s3.y;
        zz01.x = s0.z; zz01.y = s1.z;  zz23.x = s2.z; zz23.y = s3.z;
        la01.x = s0.w; la01.y = s1.w;  la23.x = s2.w; la23.y = s3.w;
    } else {
        zx01 = zy01 = zz01 = la01 = bcast(0.0f);
        zx23 = zy23 = zz23 = la23 = bcast(0.0f);
    }
    const v2f two = bcast(2.0f);

    const int nst   = ndir >> 1;               // 400 stored (half-sphere) dirs
    const int chunk = (nst + 15) >> 4;         // 25
    const int d0    = w * chunk;
    const int d1    = (d0 + chunk < nst) ? d0 + chunk : nst;

    const v2f zero = bcast(0.0f);
    v2f auv0 = zero, auv1 = zero, auv2 = zero, auv3 = zero;     // (ut,vt) moments
    v2f asv0 = zero, asv1 = zero, asv2 = zero, asv3 = zero;     // (up,vp) masked
    v2f ag0  = zero, ag1  = zero, ag2  = zero, ag3  = zero;     // (gx,gy) x-species

    // uniform scalar prefetch (SGPRs): hide SMEM latency under the body
    int dd = (d0 < d1) ? d0 : 0;
    float qx = dxp[dd], qy = dyp[dd], qz = dzp[dd], qw = qwp[dd];

    #pragma clang loop unroll(disable)
    for (int d = d0; d < d1; ++d) {
        int dn = (d + 1 < d1) ? d + 1 : d;     // clamped next index (uniform)
        float nqx = dxp[dn], nqy = dyp[dn], nqz = dzp[dn], nqw = qwp[dn];

        v2f t01 = FMA2(zx01, bcast(qx), FMA2(zy01, bcast(qy), FMA2(zz01, bcast(qz), la01)));
        v2f t23 = FMA2(zx23, bcast(qx), FMA2(zy23, bcast(qy), FMA2(zz23, bcast(qz), la23)));

        // ---- +q side ----
        {
            v2f g01, g23;
            g01.x = EXP2(t01.x); g01.y = EXP2(t01.y);
            g23.x = EXP2(t23.x); g23.y = EXP2(t23.y);
            v2f uv = bcast(qw) * (g01 - g23);          // (w*u, w*v)
            v2f wg = bcast(qw) * g23;                  // (w*g2, w*g3)
            bool c = (uv.x >= uv.y);                   // delta >= 0
            v2f suv; suv.x = c ? uv.x : 0.0f; suv.y = c ? uv.y : 0.0f;
            auv0 += uv;  auv1 = FMA2(uv, bcast(qx), auv1);
            auv2 = FMA2(uv, bcast(qy), auv2);  auv3 = FMA2(uv, bcast(qz), auv3);
            asv0 += suv; asv1 = FMA2(suv, bcast(qx), asv1);
            asv2 = FMA2(suv, bcast(qy), asv2); asv3 = FMA2(suv, bcast(qz), asv3);
            ag0  += wg;  ag1  = FMA2(wg, bcast(qx), ag1);
            ag2  = FMA2(wg, bcast(qy), ag2);   ag3  = FMA2(wg, bcast(qz), ag3);
        }
        // ---- -q side: t(-q) = 2*la - t ----
        {
            v2f n01 = FMA2(two, la01, -t01);
            v2f n23 = FMA2(two, la23, -t23);
            v2f g01, g23;
            g01.x = EXP2(n01.x); g01.y = EXP2(n01.y);
            g23.x = EXP2(n23.x); g23.y = EXP2(n23.y);
            v2f uv = bcast(qw) * (g01 - g23);
            v2f wg = bcast(qw) * g23;
            bool c = (uv.x >= uv.y);
            v2f suv; suv.x = c ? uv.x : 0.0f; suv.y = c ? uv.y : 0.0f;
            auv0 += uv;  auv1 = FMA2(uv, bcast(-qx), auv1);
            auv2 = FMA2(uv, bcast(-qy), auv2);  auv3 = FMA2(uv, bcast(-qz), auv3);
            asv0 += suv; asv1 = FMA2(suv, bcast(-qx), asv1);
            asv2 = FMA2(suv, bcast(-qy), asv2); asv3 = FMA2(suv, bcast(-qz), asv3);
            ag0  += wg;  ag1  = FMA2(wg, bcast(-qx), ag1);
            ag2  = FMA2(wg, bcast(-qy), ag2);   ag3  = FMA2(wg, bcast(-qz), ag3);
        }
        qx = nqx; qy = nqy; qz = nqz; qw = nqw;
    }

    // ---- cross-wave reduction: 2 passes x 3 float4, 2-round tree ----
    float4 rA0 = make_float4(auv0.x, auv0.y, auv1.x, auv1.y);
    float4 rA1 = make_float4(auv2.x, auv2.y, auv3.x, auv3.y);
    float4 rA2 = make_float4(asv0.x, asv0.y, asv1.x, asv1.y);
    float4 rB0 = make_float4(asv2.x, asv2.y, asv3.x, asv3.y);
    float4 rB1 = make_float4(ag0.x,  ag0.y,  ag1.x,  ag1.y);
    float4 rB2 = make_float4(ag2.x,  ag2.y,  ag3.x,  ag3.y);

    // pass A
    red[w][lane][0] = rA0; red[w][lane][1] = rA1; red[w][lane][2] = rA2;
    __syncthreads();
    if (w < 4) {
        #pragma unroll
        for (int o = 4; o < 16; o += 4) {
            add4(rA0, red[w + o][lane][0]);
            add4(rA1, red[w + o][lane][1]);
            add4(rA2, red[w + o][lane][2]);
        }
        red[w][lane][0] = rA0; red[w][lane][1] = rA1; red[w][lane][2] = rA2;
    }
    __syncthreads();
    if (w == 0) {
        #pragma unroll
        for (int o = 1; o < 4; ++o) {
            add4(rA0, red[o][lane][0]);
            add4(rA1, red[o][lane][1]);
            add4(rA2, red[o][lane][2]);
        }
    }
    __syncthreads();
    // pass B
    red[w][lane][0] = rB0; red[w][lane][1] = rB1; red[w][lane][2] = rB2;
    __syncthreads();
    if (w < 4) {
        #pragma unroll
        for (int o = 4; o < 16; o += 4) {
            add4(rB0, red[w + o][lane][0]);
            add4(rB1, red[w + o][lane][1]);
            add4(rB2, red[w + o][lane][2]);
        }
        red[w][lane][0] = rB0; red[w][lane][1] = rB1; red[w][lane][2] = rB2;
    }
    __syncthreads();
    if (w != 0 || !live) return;
    #pragma unroll
    for (int o = 1; o < 4; ++o) {
        add4(rB0, red[o][lane][0]);
        add4(rB1, red[o][lane][1]);
        add4(rB2, red[o][lane][2]);
    }

    // ---- final per-batch math (wave 0, lane = batch) ----
    float ut0 = rA0.x, vt0 = rA0.y, ut1 = rA0.z, vt1 = rA0.w;
    float ut2 = rA1.x, vt2 = rA1.y, ut3 = rA1.z, vt3 = rA1.w;
    float up0 = rA2.x, vp0 = rA2.y, up1 = rA2.z, vp1 = rA2.w;
    float up2 = rB0.x, vp2 = rB0.y, up3 = rB0.z, vp3 = rB0.w;
    float gx0 = rB1.x, gy0 = rB1.y, gx1 = rB1.z, gy1 = rB1.w;
    float gx2 = rB2.x, gy2 = rB2.y, gx3 = rB2.z, gy3 = rB2.w;

    // Iplus = up0 - vp0 (identical masked sums); Iminus = Iplus - sum w*delta
    float ip = fmaxf(up0 - vp0, 0.0f);
    float im = fmaxf(ip - ut0 + vt0, 0.0f);

    float Ips = fmaxf(ip, EPSF), Ims = fmaxf(im, EPSF);
    const float third = 1.0f / 3.0f;
    float cp, cn;
    if (ip < im) {
        cp = third;
        cn = fminf(fmaxf(1.0f - (2.0f / 3.0f) * (Ips / Ims), 0.0f), 1.0f);
    } else {
        cp = fminf(fmaxf(1.0f - (2.0f / 3.0f) * (Ims / Ips), 0.0f), 1.0f);
        cn = third;
    }

    float P0 = cp * up0 + cn * (ut0 - up0), Q0 = cp * vp0 + cn * (vt0 - vp0);
    float P1 = cp * up1 + cn * (ut1 - up1), Q1 = cp * vp1 + cn * (vt1 - vp1);
    float P2 = cp * up2 + cn * (ut2 - up2), Q2 = cp * vp2 + cn * (vt2 - vp2);
    float P3 = cp * up3 + cn * (ut3 - up3), Q3 = cp * vp3 + cn * (vt3 - vp3);

    // memory layout per batch (6 float4): [e, x, x, ebar, xbar, xbar], each (Fx,Fy,Fz,N)
    float4* o4 = (float4*)out + (size_t)b * 6;
    float4 oe = make_float4(gx1 + P1, gx2 + P2, gx3 + P3, gx0 + P0);
    float4 ox = make_float4(gx1 + 0.5f * (ut1 - P1), gx2 + 0.5f * (ut2 - P2),
                            gx3 + 0.5f * (ut3 - P3), gx0 + 0.5f * (ut0 - P0));
    float4 ob = make_float4(gy1 + Q1, gy2 + Q2, gy3 + Q3, gy0 + Q0);
    float4 oxb = make_float4(gy1 + 0.5f * (vt1 - Q1), gy2 + 0.5f * (vt2 - Q2),
                             gy3 + 0.5f * (vt3 - Q3), gy0 + 0.5f * (vt0 - Q0));
    o4[0] = oe;  o4[1] = ox;  o4[2] = ox;
    o4[3] = ob;  o4[4] = oxb; o4[5] = oxb;
    out[(size_t)B * 24 + b] = sqrtf(fmaxf(ip * im, 0.0f));      // growth
}

extern "C" void kernel_launch(void* const* d_in, const int* in_sizes, int n_in,
                              void* d_out, int out_size, void* d_ws, size_t ws_size,
                              hipStream_t stream) {
    const float* F4 = (const float*)d_in[0];
    const float* dx = (const float*)d_in[1];
    const float* dy = (const float*)d_in[2];
    const float* dz = (const float*)d_in[3];
    const float* qw = (const float*)d_in[4];
    float* out = (float*)d_out;

    int B = in_sizes[0] / 24;     // (B, 2, 3, 4)
    int ndir = in_sizes[1];       // 800
    float4* ws = (float4*)d_ws;   // B*4 float4 specs (2 MB at B=32768)

    int t1 = 4 * B;
    spec_kernel<<<(t1 + 255) / 256, 256, 0, stream>>>(F4, ws, B);
    int blocks = (B + 63) / 64;   // 64 batches per 1024-thread block
    box3d_kernel<<<blocks, 1024, 0, stream>>>(ws, dx, dy, dz, qw, out, B, ndir);
}

// Round 4
// 87.984 us; speedup vs baseline: 1.0464x; 1.0464x over previous
//
#include <hip/hip_runtime.h>
#include <math.h>

#define EPSF     1e-12f
#define INV_4PI  0.07957747154594767f
#define LOG2E    1.4426950408889634f

typedef float v2f __attribute__((ext_vector_type(2)));

#if __has_builtin(__builtin_elementwise_fma)
#define FMA2(a, b, c) __builtin_elementwise_fma((a), (b), (c))
#else
#define FMA2(a, b, c) ((a) * (b) + (c))
#endif

// hardware exp2: single v_exp_f32 (R1: poly replacement doubled issue volume)
#define EXP2(x) __builtin_amdgcn_exp2f(x)

__device__ __forceinline__ v2f bcast(float x) { v2f r; r.x = x; r.y = x; return r; }

// Z = z_approxbis(f), f already clipped to [0, 0.999999]
__device__ __forceinline__ float zapprox(float f) {
    float f2 = f * f;
    float f4 = f2 * f2;
    float f6 = f4 * f2;
    float f8 = f4 * f4;
    float denom = 3.0f - 1.00651f * f2 - 0.962251f * f4 + 1.47353f * f6 - 0.48953f * f8;
    denom = fmaxf(denom, EPSF);
    float p = 1.0f - 2.0f * (1.0f - f) * (1.0f + 1.01524f * f) / denom;
    return 2.0f * f / fmaxf(1.0f - p, 1e-6f);
}

// z / sinh(z), z >= 0
__device__ __forceinline__ float z_over_sinh(float z) {
    float zz = z * z;
    float series = 1.0f - zz / 6.0f + zz * zz / 120.0f;
    float E = __expf(z);
    float s = 0.5f * (E - 1.0f / E);
    float r = z / s;           // NaN at z==0, discarded by select
    return (z < 1e-4f) ? series : r;
}

// per-species: g(dir) = 2^(zx*dx + zy*dy + zz*dz + la)
__device__ __forceinline__ float4 setup_spec(float N, float Fx, float Fy, float Fz) {
    N = fmaxf(N, EPSF);
    float nf = sqrtf(Fx * Fx + Fy * Fy + Fz * Fz);
    float f  = fminf(fmaxf(nf / N, 0.0f), 0.999999f);
    float Z  = zapprox(f);
    float A  = N * INV_4PI * z_over_sinh(Z);
    float sc = Z * LOG2E / fmaxf(nf, EPSF);
    return make_float4(Fx * sc, Fy * sc, Fz * sc, log2f(A));
}

__device__ __forceinline__ void add4(float4& a, const float4 b) {
    a.x += b.x; a.y += b.y; a.z += b.z; a.w += b.w;
}

// ---- single fused kernel ------------------------------------------------
// R3 post-mortem: 3 structures all land ~38-40 us with ~50% of wall stalled
// (R1 counters: busy 74k vs wall 110k cyc/SIMD). Dominant chain per unit:
// dot -> 8 exps -> prep/accum, all dependent -> every wave eats exp latency
// every iteration. Fixes here:
//  * SOFTWARE PIPELINE (the change this round): issue unit d's exps, then
//    accumulate unit d-1 (independent) while they're in flight. Slot rotate
//    via #pragma unroll 2 -> register renaming, no v_mov cost.
//  * spec_kernel merged in-block (256-thread LDS handoff): kills one
//    dispatch + inter-kernel gap, drops the d_ws dependency.
//  * accumulation: independent +q/-q sides with neg-modifier FMAs (same
//    semantics as R3 -> absmax unchanged).
// Geometry kept from R3: lane=batch (64/wave), wave=25-dir chunk (16 waves
// x 25 = 400 exact), 512 blocks x 1024 thr = 2 blocks/CU = 8 waves/SIMD at
// VGPR<=64 (live set budgeted: consts 16 + accums 24 + 2 slots x 8 ~ 60).
__global__ __launch_bounds__(1024, 8) void box3d_kernel(
    const float* __restrict__ F4,
    const float* __restrict__ dxp, const float* __restrict__ dyp,
    const float* __restrict__ dzp, const float* __restrict__ qwp,
    float* __restrict__ out, int B, int ndir)
{
    __shared__ float4 sh_spec[4][64];          // 4 KiB
    __shared__ float4 red[16][64][3];          // 48 KiB

    const int tid  = threadIdx.x;
    const int lane = tid & 63;
    const int w    = __builtin_amdgcn_readfirstlane(tid >> 6);   // 0..15
    const int base = blockIdx.x * 64;
    const int b    = base + lane;

    // ---- inline spec: threads 0..255 cover (species, batch-local) ----
    if (tid < 256) {
        int bl = tid & 63, s = tid >> 6;
        int bb = base + bl;
        float N = 1.0f, Fx = 0.0f, Fy = 0.0f, Fz = 0.0f;
        if (bb < B) {
            const float4* row = (const float4*)(F4 + (size_t)bb * 24);
            if (s == 0) {                       // e
                float4 a = row[0];  N = a.w; Fx = a.x; Fy = a.y; Fz = a.z;
            } else if (s == 1) {                // ebar
                float4 a = row[3];  N = a.w; Fx = a.x; Fy = a.y; Fz = a.z;
            } else if (s == 2) {                // x = mean(flavors 1,2) of nu
                float4 a = row[1], c = row[2];
                N = 0.5f * (a.w + c.w); Fx = 0.5f * (a.x + c.x);
                Fy = 0.5f * (a.y + c.y); Fz = 0.5f * (a.z + c.z);
            } else {                            // xbar
                float4 a = row[4], c = row[5];
                N = 0.5f * (a.w + c.w); Fx = 0.5f * (a.x + c.x);
                Fy = 0.5f * (a.y + c.y); Fz = 0.5f * (a.z + c.z);
            }
        }
        sh_spec[s][bl] = setup_spec(N, Fx, Fy, Fz);
    }
    __syncthreads();

    float4 f0 = sh_spec[0][lane], f1 = sh_spec[1][lane];
    float4 f2 = sh_spec[2][lane], f3 = sh_spec[3][lane];
    // packed species constants: (e,ebar) and (x,xbar)
    v2f zx01, zy01, zz01, la01, zx23, zy23, zz23, la23;
    zx01.x = f0.x; zx01.y = f1.x;  zx23.x = f2.x; zx23.y = f3.x;
    zy01.x = f0.y; zy01.y = f1.y;  zy23.x = f2.y; zy23.y = f3.y;
    zz01.x = f0.z; zz01.y = f1.z;  zz23.x = f2.z; zz23.y = f3.z;
    la01.x = f0.w; la01.y = f1.w;  la23.x = f2.w; la23.y = f3.w;
    const v2f two = bcast(2.0f);

    const int nst   = ndir >> 1;               // 400 stored (half-sphere) dirs
    const int chunk = (nst + 15) >> 4;         // 25
    const int d0    = w * chunk;
    const int d1    = (d0 + chunk < nst) ? d0 + chunk : nst;

    const v2f zero = bcast(0.0f);
    v2f auv0 = zero, auv1 = zero, auv2 = zero, auv3 = zero;     // (ut,vt)
    v2f asv0 = zero, asv1 = zero, asv2 = zero, asv3 = zero;     // (up,vp) masked
    v2f ag0  = zero, ag1  = zero, ag2  = zero, ag3  = zero;     // (gx,gy)

    // ---- pipeline slot: prev unit's exp'd g values + its q ----
    v2f Pg01, Pg23, Ng01, Ng23;
    float pqx, pqy, pqz, pqw;
    {
        int dd = (d0 < d1) ? d0 : 0;
        pqx = dxp[dd]; pqy = dyp[dd]; pqz = dzp[dd]; pqw = qwp[dd];
        v2f t01 = FMA2(zx01, bcast(pqx), FMA2(zy01, bcast(pqy), FMA2(zz01, bcast(pqz), la01)));
        v2f t23 = FMA2(zx23, bcast(pqx), FMA2(zy23, bcast(pqy), FMA2(zz23, bcast(pqz), la23)));
        v2f n01 = FMA2(two, la01, -t01);       // antipode: 2*la - t
        v2f n23 = FMA2(two, la23, -t23);
        Pg01.x = EXP2(t01.x); Pg01.y = EXP2(t01.y);
        Pg23.x = EXP2(t23.x); Pg23.y = EXP2(t23.y);
        Ng01.x = EXP2(n01.x); Ng01.y = EXP2(n01.y);
        Ng23.x = EXP2(n23.x); Ng23.y = EXP2(n23.y);
    }

    // accumulate one unit's 8 g's (both hemispheres) with its q
#define ACCUM_UNIT(G01P, G23P, G01N, G23N, QX, QY, QZ, QW)                         \
    {                                                                              \
        v2f uvP = ((G01P) - (G23P)) * bcast(QW);                                   \
        v2f wgP = bcast(QW) * (G23P);                                              \
        bool cP = (uvP.x >= uvP.y);                                                \
        v2f suvP; suvP.x = cP ? uvP.x : 0.0f; suvP.y = cP ? uvP.y : 0.0f;          \
        auv0 += uvP;  auv1 = FMA2(uvP, bcast(QX), auv1);                           \
        auv2 = FMA2(uvP, bcast(QY), auv2);  auv3 = FMA2(uvP, bcast(QZ), auv3);     \
        asv0 += suvP; asv1 = FMA2(suvP, bcast(QX), asv1);                          \
        asv2 = FMA2(suvP, bcast(QY), asv2); asv3 = FMA2(suvP, bcast(QZ), asv3);    \
        ag0  += wgP;  ag1  = FMA2(wgP, bcast(QX), ag1);                            \
        ag2  = FMA2(wgP, bcast(QY), ag2);   ag3  = FMA2(wgP, bcast(QZ), ag3);      \
        v2f uvN = ((G01N) - (G23N)) * bcast(QW);                                   \
        v2f wgN = bcast(QW) * (G23N);                                              \
        bool cN = (uvN.x >= uvN.y);                                                \
        v2f suvN; suvN.x = cN ? uvN.x : 0.0f; suvN.y = cN ? uvN.y : 0.0f;          \
        auv0 += uvN;  auv1 = FMA2(uvN, bcast(-(QX)), auv1);                        \
        auv2 = FMA2(uvN, bcast(-(QY)), auv2);  auv3 = FMA2(uvN, bcast(-(QZ)), auv3);\
        asv0 += suvN; asv1 = FMA2(suvN, bcast(-(QX)), asv1);                       \
        asv2 = FMA2(suvN, bcast(-(QY)), asv2); asv3 = FMA2(suvN, bcast(-(QZ)), asv3);\
        ag0  += wgN;  ag1  = FMA2(wgN, bcast(-(QX)), ag1);                         \
        ag2  = FMA2(wgN, bcast(-(QY)), ag2);   ag3  = FMA2(wgN, bcast(-(QZ)), ag3);\
    }

    // steady state: issue exps for unit d, retire unit d-1 under them
    #pragma unroll 2
    for (int d = d0 + 1; d < d1; ++d) {
        float qx = dxp[d], qy = dyp[d], qz = dzp[d], qw = qwp[d];
        v2f t01 = FMA2(zx01, bcast(qx), FMA2(zy01, bcast(qy), FMA2(zz01, bcast(qz), la01)));
        v2f t23 = FMA2(zx23, bcast(qx), FMA2(zy23, bcast(qy), FMA2(zz23, bcast(qz), la23)));
        v2f n01 = FMA2(two, la01, -t01);
        v2f n23 = FMA2(two, la23, -t23);
        v2f Cg01, Cg23, Cn01, Cn23;
        Cg01.x = EXP2(t01.x); Cg01.y = EXP2(t01.y);
        Cg23.x = EXP2(t23.x); Cg23.y = EXP2(t23.y);
        Cn01.x = EXP2(n01.x); Cn01.y = EXP2(n01.y);
        Cn23.x = EXP2(n23.x); Cn23.y = EXP2(n23.y);

        ACCUM_UNIT(Pg01, Pg23, Ng01, Ng23, pqx, pqy, pqz, pqw);

        Pg01 = Cg01; Pg23 = Cg23; Ng01 = Cn01; Ng23 = Cn23;
        pqx = qx; pqy = qy; pqz = qz; pqw = qw;
    }
    // drain last unit
    ACCUM_UNIT(Pg01, Pg23, Ng01, Ng23, pqx, pqy, pqz, pqw);
#undef ACCUM_UNIT

    // ---- cross-wave reduction: 2 passes x 3 float4, 2-round tree ----
    float4 rA0 = make_float4(auv0.x, auv0.y, auv1.x, auv1.y);
    float4 rA1 = make_float4(auv2.x, auv2.y, auv3.x, auv3.y);
    float4 rA2 = make_float4(asv0.x, asv0.y, asv1.x, asv1.y);
    float4 rB0 = make_float4(asv2.x, asv2.y, asv3.x, asv3.y);
    float4 rB1 = make_float4(ag0.x,  ag0.y,  ag1.x,  ag1.y);
    float4 rB2 = make_float4(ag2.x,  ag2.y,  ag3.x,  ag3.y);

    __syncthreads();   // sh_spec reads done before red reuse barrier below
    // pass A
    red[w][lane][0] = rA0; red[w][lane][1] = rA1; red[w][lane][2] = rA2;
    __syncthreads();
    if (w < 4) {
        #pragma unroll
        for (int o = 4; o < 16; o += 4) {
            add4(rA0, red[w + o][lane][0]);
            add4(rA1, red[w + o][lane][1]);
            add4(rA2, red[w + o][lane][2]);
        }
        red[w][lane][0] = rA0; red[w][lane][1] = rA1; red[w][lane][2] = rA2;
    }
    __syncthreads();
    if (w == 0) {
        #pragma unroll
        for (int o = 1; o < 4; ++o) {
            add4(rA0, red[o][lane][0]);
            add4(rA1, red[o][lane][1]);
            add4(rA2, red[o][lane][2]);
        }
    }
    __syncthreads();
    // pass B
    red[w][lane][0] = rB0; red[w][lane][1] = rB1; red[w][lane][2] = rB2;
    __syncthreads();
    if (w < 4) {
        #pragma unroll
        for (int o = 4; o < 16; o += 4) {
            add4(rB0, red[w + o][lane][0]);
            add4(rB1, red[w + o][lane][1]);
            add4(rB2, red[w + o][lane][2]);
        }
        red[w][lane][0] = rB0; red[w][lane][1] = rB1; red[w][lane][2] = rB2;
    }
    __syncthreads();
    if (w != 0 || b >= B) return;
    #pragma unroll
    for (int o = 1; o < 4; ++o) {
        add4(rB0, red[o][lane][0]);
        add4(rB1, red[o][lane][1]);
        add4(rB2, red[o][lane][2]);
    }

    // ---- final per-batch math (wave 0, lane = batch) ----
    float ut0 = rA0.x, vt0 = rA0.y, ut1 = rA0.z, vt1 = rA0.w;
    float ut2 = rA1.x, vt2 = rA1.y, ut3 = rA1.z, vt3 = rA1.w;
    float up0 = rA2.x, vp0 = rA2.y, up1 = rA2.z, vp1 = rA2.w;
    float up2 = rB0.x, vp2 = rB0.y, up3 = rB0.z, vp3 = rB0.w;
    float gx0 = rB1.x, gy0 = rB1.y, gx1 = rB1.z, gy1 = rB1.w;
    float gx2 = rB2.x, gy2 = rB2.y, gx3 = rB2.z, gy3 = rB2.w;

    // Iplus = up0 - vp0 (identical masked sums); Iminus = Iplus - sum w*delta
    float ip = fmaxf(up0 - vp0, 0.0f);
    float im = fmaxf(ip - ut0 + vt0, 0.0f);

    float Ips = fmaxf(ip, EPSF), Ims = fmaxf(im, EPSF);
    const float third = 1.0f / 3.0f;
    float cp, cn;
    if (ip < im) {
        cp = third;
        cn = fminf(fmaxf(1.0f - (2.0f / 3.0f) * (Ips / Ims), 0.0f), 1.0f);
    } else {
        cp = fminf(fmaxf(1.0f - (2.0f / 3.0f) * (Ims / Ips), 0.0f), 1.0f);
        cn = third;
    }

    float P0 = cp * up0 + cn * (ut0 - up0), Q0 = cp * vp0 + cn * (vt0 - vp0);
    float P1 = cp * up1 + cn * (ut1 - up1), Q1 = cp * vp1 + cn * (vt1 - vp1);
    float P2 = cp * up2 + cn * (ut2 - up2), Q2 = cp * vp2 + cn * (vt2 - vp2);
    float P3 = cp * up3 + cn * (ut3 - up3), Q3 = cp * vp3 + cn * (vt3 - vp3);

    // memory layout per batch (6 float4): [e, x, x, ebar, xbar, xbar], each (Fx,Fy,Fz,N)
    float4* o4 = (float4*)out + (size_t)b * 6;
    float4 oe = make_float4(gx1 + P1, gx2 + P2, gx3 + P3, gx0 + P0);
    float4 ox = make_float4(gx1 + 0.5f * (ut1 - P1), gx2 + 0.5f * (ut2 - P2),
                            gx3 + 0.5f * (ut3 - P3), gx0 + 0.5f * (ut0 - P0));
    float4 ob = make_float4(gy1 + Q1, gy2 + Q2, gy3 + Q3, gy0 + Q0);
    float4 oxb = make_float4(gy1 + 0.5f * (vt1 - Q1), gy2 + 0.5f * (vt2 - Q2),
                             gy3 + 0.5f * (vt3 - Q3), gy0 + 0.5f * (vt0 - Q0));
    o4[0] = oe;  o4[1] = ox;  o4[2] = ox;
    o4[3] = ob;  o4[4] = oxb; o4[5] = oxb;
    out[(size_t)B * 24 + b] = sqrtf(fmaxf(ip * im, 0.0f));      // growth
}

extern "C" void kernel_launch(void* const* d_in, const int* in_sizes, int n_in,
                              void* d_out, int out_size, void* d_ws, size_t ws_size,
                              hipStream_t stream) {
    const float* F4 = (const float*)d_in[0];
    const float* dx = (const float*)d_in[1];
    const float* dy = (const float*)d_in[2];
    const float* dz = (const float*)d_in[3];
    const float* qw = (const float*)d_in[4];
    float* out = (float*)d_out;

    int B = in_sizes[0] / 24;     // (B, 2, 3, 4)
    int ndir = in_sizes[1];       // 800
    (void)d_ws; (void)ws_size;    // workspace no longer needed (spec inlined)

    int blocks = (B + 63) / 64;   // 64 batches per 1024-thread block
    box3d_kernel<<<blocks, 1024, 0, stream>>>(F4, dx, dy, dz, qw, out, B, ndir);
}

// Round 5
// 87.924 us; speedup vs baseline: 1.0471x; 1.0007x over previous
//
#include <hip/hip_runtime.h>
#include <math.h>

#define EPSF     1e-12f
#define INV_4PI  0.07957747154594767f
#define LOG2E    1.4426950408889634f

typedef float v2f __attribute__((ext_vector_type(2)));

#if __has_builtin(__builtin_elementwise_fma)
#define FMA2(a, b, c) __builtin_elementwise_fma((a), (b), (c))
#else
#define FMA2(a, b, c) ((a) * (b) + (c))
#endif

// hardware exp2: single v_exp_f32 (R1: poly replacement doubled issue volume)
#define EXP2(x) __builtin_amdgcn_exp2f(x)

__device__ __forceinline__ v2f bcast(float x) { v2f r; r.x = x; r.y = x; return r; }

// Z = z_approxbis(f), f already clipped to [0, 0.999999]
__device__ __forceinline__ float zapprox(float f) {
    float f2 = f * f;
    float f4 = f2 * f2;
    float f6 = f4 * f2;
    float f8 = f4 * f4;
    float denom = 3.0f - 1.00651f * f2 - 0.962251f * f4 + 1.47353f * f6 - 0.48953f * f8;
    denom = fmaxf(denom, EPSF);
    float p = 1.0f - 2.0f * (1.0f - f) * (1.0f + 1.01524f * f) / denom;
    return 2.0f * f / fmaxf(1.0f - p, 1e-6f);
}

// z / sinh(z), z >= 0
__device__ __forceinline__ float z_over_sinh(float z) {
    float zz = z * z;
    float series = 1.0f - zz / 6.0f + zz * zz / 120.0f;
    float E = __expf(z);
    float s = 0.5f * (E - 1.0f / E);
    float r = z / s;           // NaN at z==0, discarded by select
    return (z < 1e-4f) ? series : r;
}

// per-species: g(dir) = 2^(zx*dx + zy*dy + zz*dz + la)
__device__ __forceinline__ float4 setup_spec(float N, float Fx, float Fy, float Fz) {
    N = fmaxf(N, EPSF);
    float nf = sqrtf(Fx * Fx + Fy * Fy + Fz * Fz);
    float f  = fminf(fmaxf(nf / N, 0.0f), 0.999999f);
    float Z  = zapprox(f);
    float A  = N * INV_4PI * z_over_sinh(Z);
    float sc = Z * LOG2E / fmaxf(nf, EPSF);
    return make_float4(Fx * sc, Fy * sc, Fz * sc, log2f(A));
}

__device__ __forceinline__ void add4(float4& a, const float4 b) {
    a.x += b.x; a.y += b.y; a.z += b.z; a.w += b.w;
}

// ---- single fused kernel ------------------------------------------------
// R4 post-mortem: at max occupancy (8 waves/SIMD = 32/CU cap) + explicit
// pipelining, box3d sits ~40 us ~ 88% of the serial trans+VALU issue floor
// (exp ~32 cyc/wave-inst serial-additive; 8 exps/unit irreducible).
// This round: s/d accumulation (R1-proven algebra) — accumulate hemisphere
// SUM into moment-0 and hemisphere DIFF into the q-weighted moments:
//   acc0 += (P+N);  acc_m += (P-N)*q_m      (P at +q, N at -q)
// 18 pk accum ops/unit instead of 24, and drops the -q FMA variants.
// Everything else unchanged from R4 (pipeline via unroll 2, inline spec,
// lane=batch / wave=dir-chunk geometry, 2-block/CU residency).
__global__ __launch_bounds__(1024, 8) void box3d_kernel(
    const float* __restrict__ F4,
    const float* __restrict__ dxp, const float* __restrict__ dyp,
    const float* __restrict__ dzp, const float* __restrict__ qwp,
    float* __restrict__ out, int B, int ndir)
{
    __shared__ float4 sh_spec[4][64];          // 4 KiB
    __shared__ float4 red[16][64][3];          // 48 KiB

    const int tid  = threadIdx.x;
    const int lane = tid & 63;
    const int w    = __builtin_amdgcn_readfirstlane(tid >> 6);   // 0..15
    const int base = blockIdx.x * 64;
    const int b    = base + lane;

    // ---- inline spec: threads 0..255 cover (species, batch-local) ----
    if (tid < 256) {
        int bl = tid & 63, s = tid >> 6;
        int bb = base + bl;
        float N = 1.0f, Fx = 0.0f, Fy = 0.0f, Fz = 0.0f;
        if (bb < B) {
            const float4* row = (const float4*)(F4 + (size_t)bb * 24);
            if (s == 0) {                       // e
                float4 a = row[0];  N = a.w; Fx = a.x; Fy = a.y; Fz = a.z;
            } else if (s == 1) {                // ebar
                float4 a = row[3];  N = a.w; Fx = a.x; Fy = a.y; Fz = a.z;
            } else if (s == 2) {                // x = mean(flavors 1,2) of nu
                float4 a = row[1], c = row[2];
                N = 0.5f * (a.w + c.w); Fx = 0.5f * (a.x + c.x);
                Fy = 0.5f * (a.y + c.y); Fz = 0.5f * (a.z + c.z);
            } else {                            // xbar
                float4 a = row[4], c = row[5];
                N = 0.5f * (a.w + c.w); Fx = 0.5f * (a.x + c.x);
                Fy = 0.5f * (a.y + c.y); Fz = 0.5f * (a.z + c.z);
            }
        }
        sh_spec[s][bl] = setup_spec(N, Fx, Fy, Fz);
    }
    __syncthreads();

    float4 f0 = sh_spec[0][lane], f1 = sh_spec[1][lane];
    float4 f2 = sh_spec[2][lane], f3 = sh_spec[3][lane];
    // packed species constants: (e,ebar) and (x,xbar)
    v2f zx01, zy01, zz01, la01, zx23, zy23, zz23, la23;
    zx01.x = f0.x; zx01.y = f1.x;  zx23.x = f2.x; zx23.y = f3.x;
    zy01.x = f0.y; zy01.y = f1.y;  zy23.x = f2.y; zy23.y = f3.y;
    zz01.x = f0.z; zz01.y = f1.z;  zz23.x = f2.z; zz23.y = f3.z;
    la01.x = f0.w; la01.y = f1.w;  la23.x = f2.w; la23.y = f3.w;
    const v2f two = bcast(2.0f);

    const int nst   = ndir >> 1;               // 400 stored (half-sphere) dirs
    const int chunk = (nst + 15) >> 4;         // 25
    const int d0    = w * chunk;
    const int d1    = (d0 + chunk < nst) ? d0 + chunk : nst;

    const v2f zero = bcast(0.0f);
    v2f auv0 = zero, auv1 = zero, auv2 = zero, auv3 = zero;     // (ut,vt)
    v2f asv0 = zero, asv1 = zero, asv2 = zero, asv3 = zero;     // (up,vp) masked
    v2f ag0  = zero, ag1  = zero, ag2  = zero, ag3  = zero;     // (gx,gy)

    // ---- pipeline slot: prev unit's exp'd g values + its q ----
    v2f Pg01, Pg23, Ng01, Ng23;
    float pqx, pqy, pqz, pqw;
    {
        int dd = (d0 < d1) ? d0 : 0;
        pqx = dxp[dd]; pqy = dyp[dd]; pqz = dzp[dd]; pqw = qwp[dd];
        v2f t01 = FMA2(zx01, bcast(pqx), FMA2(zy01, bcast(pqy), FMA2(zz01, bcast(pqz), la01)));
        v2f t23 = FMA2(zx23, bcast(pqx), FMA2(zy23, bcast(pqy), FMA2(zz23, bcast(pqz), la23)));
        v2f n01 = FMA2(two, la01, -t01);       // antipode: 2*la - t
        v2f n23 = FMA2(two, la23, -t23);
        Pg01.x = EXP2(t01.x); Pg01.y = EXP2(t01.y);
        Pg23.x = EXP2(t23.x); Pg23.y = EXP2(t23.y);
        Ng01.x = EXP2(n01.x); Ng01.y = EXP2(n01.y);
        Ng23.x = EXP2(n23.x); Ng23.y = EXP2(n23.y);
    }

    // accumulate one unit's 8 g's (both hemispheres) with its q.
    // s/d form: +q side P, -q side N -> acc0 += P+N, acc_m += (P-N)*q_m
#define ACCUM_UNIT(G01P, G23P, G01N, G23N, QX, QY, QZ, QW)                         \
    {                                                                              \
        v2f wq = bcast(QW);                                                        \
        v2f uvP = ((G01P) - (G23P)) * wq;                                          \
        v2f uvN = ((G01N) - (G23N)) * wq;                                          \
        v2f wgP = wq * (G23P);                                                     \
        v2f wgN = wq * (G23N);                                                     \
        bool cP = (uvP.x >= uvP.y);                                                \
        bool cN = (uvN.x >= uvN.y);                                                \
        v2f suvP; suvP.x = cP ? uvP.x : 0.0f; suvP.y = cP ? uvP.y : 0.0f;          \
        v2f suvN; suvN.x = cN ? uvN.x : 0.0f; suvN.y = cN ? uvN.y : 0.0f;          \
        v2f s, d;                                                                  \
        s = uvP + uvN;   d = uvP - uvN;                                            \
        auv0 += s;  auv1 = FMA2(d, bcast(QX), auv1);                               \
        auv2 = FMA2(d, bcast(QY), auv2);  auv3 = FMA2(d, bcast(QZ), auv3);         \
        s = suvP + suvN; d = suvP - suvN;                                          \
        asv0 += s;  asv1 = FMA2(d, bcast(QX), asv1);                               \
        asv2 = FMA2(d, bcast(QY), asv2);  asv3 = FMA2(d, bcast(QZ), asv3);         \
        s = wgP + wgN;   d = wgP - wgN;                                            \
        ag0  += s;  ag1  = FMA2(d, bcast(QX), ag1);                                \
        ag2  = FMA2(d, bcast(QY), ag2);   ag3  = FMA2(d, bcast(QZ), ag3);          \
    }

    // steady state: issue exps for unit d, retire unit d-1 under them
    #pragma unroll 2
    for (int d = d0 + 1; d < d1; ++d) {
        float qx = dxp[d], qy = dyp[d], qz = dzp[d], qw = qwp[d];
        v2f t01 = FMA2(zx01, bcast(qx), FMA2(zy01, bcast(qy), FMA2(zz01, bcast(qz), la01)));
        v2f t23 = FMA2(zx23, bcast(qx), FMA2(zy23, bcast(qy), FMA2(zz23, bcast(qz), la23)));
        v2f n01 = FMA2(two, la01, -t01);
        v2f n23 = FMA2(two, la23, -t23);
        v2f Cg01, Cg23, Cn01, Cn23;
        Cg01.x = EXP2(t01.x); Cg01.y = EXP2(t01.y);
        Cg23.x = EXP2(t23.x); Cg23.y = EXP2(t23.y);
        Cn01.x = EXP2(n01.x); Cn01.y = EXP2(n01.y);
        Cn23.x = EXP2(n23.x); Cn23.y = EXP2(n23.y);

        ACCUM_UNIT(Pg01, Pg23, Ng01, Ng23, pqx, pqy, pqz, pqw);

        Pg01 = Cg01; Pg23 = Cg23; Ng01 = Cn01; Ng23 = Cn23;
        pqx = qx; pqy = qy; pqz = qz; pqw = qw;
    }
    // drain last unit
    ACCUM_UNIT(Pg01, Pg23, Ng01, Ng23, pqx, pqy, pqz, pqw);
#undef ACCUM_UNIT

    // ---- cross-wave reduction: 2 passes x 3 float4, 2-round tree ----
    float4 rA0 = make_float4(auv0.x, auv0.y, auv1.x, auv1.y);
    float4 rA1 = make_float4(auv2.x, auv2.y, auv3.x, auv3.y);
    float4 rA2 = make_float4(asv0.x, asv0.y, asv1.x, asv1.y);
    float4 rB0 = make_float4(asv2.x, asv2.y, asv3.x, asv3.y);
    float4 rB1 = make_float4(ag0.x,  ag0.y,  ag1.x,  ag1.y);
    float4 rB2 = make_float4(ag2.x,  ag2.y,  ag3.x,  ag3.y);

    __syncthreads();
    // pass A
    red[w][lane][0] = rA0; red[w][lane][1] = rA1; red[w][lane][2] = rA2;
    __syncthreads();
    if (w < 4) {
        #pragma unroll
        for (int o = 4; o < 16; o += 4) {
            add4(rA0, red[w + o][lane][0]);
            add4(rA1, red[w + o][lane][1]);
            add4(rA2, red[w + o][lane][2]);
        }
        red[w][lane][0] = rA0; red[w][lane][1] = rA1; red[w][lane][2] = rA2;
    }
    __syncthreads();
    if (w == 0) {
        #pragma unroll
        for (int o = 1; o < 4; ++o) {
            add4(rA0, red[o][lane][0]);
            add4(rA1, red[o][lane][1]);
            add4(rA2, red[o][lane][2]);
        }
    }
    __syncthreads();
    // pass B
    red[w][lane][0] = rB0; red[w][lane][1] = rB1; red[w][lane][2] = rB2;
    __syncthreads();
    if (w < 4) {
        #pragma unroll
        for (int o = 4; o < 16; o += 4) {
            add4(rB0, red[w + o][lane][0]);
            add4(rB1, red[w + o][lane][1]);
            add4(rB2, red[w + o][lane][2]);
        }
        red[w][lane][0] = rB0; red[w][lane][1] = rB1; red[w][lane][2] = rB2;
    }
    __syncthreads();
    if (w != 0 || b >= B) return;
    #pragma unroll
    for (int o = 1; o < 4; ++o) {
        add4(rB0, red[o][lane][0]);
        add4(rB1, red[o][lane][1]);
        add4(rB2, red[o][lane][2]);
    }

    // ---- final per-batch math (wave 0, lane = batch) ----
    float ut0 = rA0.x, vt0 = rA0.y, ut1 = rA0.z, vt1 = rA0.w;
    float ut2 = rA1.x, vt2 = rA1.y, ut3 = rA1.z, vt3 = rA1.w;
    float up0 = rA2.x, vp0 = rA2.y, up1 = rA2.z, vp1 = rA2.w;
    float up2 = rB0.x, vp2 = rB0.y, up3 = rB0.z, vp3 = rB0.w;
    float gx0 = rB1.x, gy0 = rB1.y, gx1 = rB1.z, gy1 = rB1.w;
    float gx2 = rB2.x, gy2 = rB2.y, gx3 = rB2.z, gy3 = rB2.w;

    // Iplus = up0 - vp0 (identical masked sums); Iminus = Iplus - sum w*delta
    float ip = fmaxf(up0 - vp0, 0.0f);
    float im = fmaxf(ip - ut0 + vt0, 0.0f);

    float Ips = fmaxf(ip, EPSF), Ims = fmaxf(im, EPSF);
    const float third = 1.0f / 3.0f;
    float cp, cn;
    if (ip < im) {
        cp = third;
        cn = fminf(fmaxf(1.0f - (2.0f / 3.0f) * (Ips / Ims), 0.0f), 1.0f);
    } else {
        cp = fminf(fmaxf(1.0f - (2.0f / 3.0f) * (Ims / Ips), 0.0f), 1.0f);
        cn = third;
    }

    float P0 = cp * up0 + cn * (ut0 - up0), Q0 = cp * vp0 + cn * (vt0 - vp0);
    float P1 = cp * up1 + cn * (ut1 - up1), Q1 = cp * vp1 + cn * (vt1 - vp1);
    float P2 = cp * up2 + cn * (ut2 - up2), Q2 = cp * vp2 + cn * (vt2 - vp2);
    float P3 = cp * up3 + cn * (ut3 - up3), Q3 = cp * vp3 + cn * (vt3 - vp3);

    // memory layout per batch (6 float4): [e, x, x, ebar, xbar, xbar], each (Fx,Fy,Fz,N)
    float4* o4 = (float4*)out + (size_t)b * 6;
    float4 oe = make_float4(gx1 + P1, gx2 + P2, gx3 + P3, gx0 + P0);
    float4 ox = make_float4(gx1 + 0.5f * (ut1 - P1), gx2 + 0.5f * (ut2 - P2),
                            gx3 + 0.5f * (ut3 - P3), gx0 + 0.5f * (ut0 - P0));
    float4 ob = make_float4(gy1 + Q1, gy2 + Q2, gy3 + Q3, gy0 + Q0);
    float4 oxb = make_float4(gy1 + 0.5f * (vt1 - Q1), gy2 + 0.5f * (vt2 - Q2),
                             gy3 + 0.5f * (vt3 - Q3), gy0 + 0.5f * (vt0 - Q0));
    o4[0] = oe;  o4[1] = ox;  o4[2] = ox;
    o4[3] = ob;  o4[4] = oxb; o4[5] = oxb;
    out[(size_t)B * 24 + b] = sqrtf(fmaxf(ip * im, 0.0f));      // growth
}

extern "C" void kernel_launch(void* const* d_in, const int* in_sizes, int n_in,
                              void* d_out, int out_size, void* d_ws, size_t ws_size,
                              hipStream_t stream) {
    const float* F4 = (const float*)d_in[0];
    const float* dx = (const float*)d_in[1];
    const float* dy = (const float*)d_in[2];
    const float* dz = (const float*)d_in[3];
    const float* qw = (const float*)d_in[4];
    float* out = (float*)d_out;

    int B = in_sizes[0] / 24;     // (B, 2, 3, 4)
    int ndir = in_sizes[1];       // 800
    (void)d_ws; (void)ws_size;    // workspace unused (spec inlined)

    int blocks = (B + 63) / 64;   // 64 batches per 1024-thread block
    box3d_kernel<<<blocks, 1024, 0, stream>>>(F4, dx, dy, dz, qw, out, B, ndir);
}